// Round 1
// baseline (359.500 us; speedup 1.0000x reference)
//
#include <hip/hip_runtime.h>
#include <math.h>

#define N_ROWS 32768
#define N_COLS 2048
constexpr float S_CONST = 1.05f;

// Butterfly reductions: result valid in ALL 64 lanes (no broadcast needed).
__device__ __forceinline__ float wred_sum(float v) {
    #pragma unroll
    for (int off = 32; off > 0; off >>= 1) v += __shfl_xor(v, off, 64);
    return v;
}
__device__ __forceinline__ float wred_max(float v) {
    #pragma unroll
    for (int off = 32; off > 0; off >>= 1) v = fmaxf(v, __shfl_xor(v, off, 64));
    return v;
}

// Single dispatch replacing two hipMemsetAsync: zero class accumulators + out.
__global__ __launch_bounds__(256) void k_init(float* __restrict__ ws,
                                              float* __restrict__ out) {
    int i = blockIdx.x * 256 + threadIdx.x;
    if (i < 3 * N_COLS) ws[i] = 0.f;
    if (i == 0) out[0] = 0.f;
}

// ONE WAVE PER ROW (4 rows / 256-thread block). Each lane: 8 float4 loads
// (32 cols), issued back-to-back for MLP. All reductions are in-register
// shfl butterflies — no LDS, no __syncthreads. Single pass over 256 MB.
// Target-column handling is wave-uniform-decoded: (tk, tc) are uniform,
// only the owner lane predicates — ~10 VALU ops instead of 32x(cmp+2 sel).
__global__ __launch_bounds__(256) void k_rowpass(
    const float* __restrict__ X, const long long* __restrict__ lbl,
    float* __restrict__ g_sum, float* __restrict__ g_sq, float* __restrict__ g_cnt,
    float* __restrict__ row_lse, float* __restrict__ row_lc)
{
    const int lane = threadIdx.x & 63;
    const int row  = blockIdx.x * 4 + (threadIdx.x >> 6);
    const int col  = (int)lbl[row];
    const int  tk    = col >> 8;               // float4 slot of target (uniform)
    const int  tc    = col & 3;                // component of target   (uniform)
    const bool owner = (lane == ((col >> 2) & 63));

    const float4* xr = (const float4*)(X + (size_t)row * N_COLS);
    float4 v[8];
    #pragma unroll
    for (int k = 0; k < 8; k++) v[k] = xr[lane + 64 * k];  // 8 outstanding dwordx4

    float sum = 0.f, sq = 0.f, mx = -INFINITY, lc = 0.f;
    #pragma unroll
    for (int k = 0; k < 8; k++) {
        float e0 = v[k].x, e1 = v[k].y, e2 = v[k].z, e3 = v[k].w;
        sum += e0 + e1 + e2 + e3;                    // class stats INCLUDE target
        sq = fmaf(e0, e0, sq); sq = fmaf(e1, e1, sq);
        sq = fmaf(e2, e2, sq); sq = fmaf(e3, e3, sq);
        if (k == tk) {                               // wave-uniform branch
            float te = (tc == 0) ? e0 : (tc == 1) ? e1 : (tc == 2) ? e2 : e3;
            if (owner) {                             // single-lane predication
                lc = te;
                if (tc == 0)      e0 = -INFINITY;    // exclude target from max/sumexp
                else if (tc == 1) e1 = -INFINITY;
                else if (tc == 2) e2 = -INFINITY;
                else              e3 = -INFINITY;
                v[k] = make_float4(e0, e1, e2, e3);
            }
        }
        mx = fmaxf(fmaxf(mx, fmaxf(e0, e1)), fmaxf(e2, e3));
    }
    sum = wred_sum(sum);
    sq  = wred_sum(sq);
    mx  = wred_max(mx);
    lc  = __shfl(lc, (col >> 2) & 63, 64);   // owning lane -> all lanes

    float se = 0.f;
    #pragma unroll
    for (int k = 0; k < 8; k++) {
        se += __expf(v[k].x - mx);           // exp(-inf)=0 drops the target col
        se += __expf(v[k].y - mx);
        se += __expf(v[k].z - mx);
        se += __expf(v[k].w - mx);
    }
    se = wred_sum(se);

    if (lane == 0) {
        row_lse[row] = mx + logf(se);        // fused: lse over non-target cols
        row_lc[row]  = lc;
        atomicAdd(&g_sum[col], sum);
        atomicAdd(&g_sq[col],  sq);
        atomicAdd(&g_cnt[col], 1.0f);
    }
}

// Per-row epilogue: exactly one row per thread (128 blocks x 256 = 32768).
// m[c] computed inline from class sums (L2-resident 24 KB arrays).
// nll = logsumexp(row_lse, val) - val; mean accumulated into out[0].
__global__ __launch_bounds__(256) void k_nll(
    const long long* __restrict__ lbl,
    const float* __restrict__ g_sum, const float* __restrict__ g_sq,
    const float* __restrict__ g_cnt,
    const float* __restrict__ row_lse, const float* __restrict__ row_lc,
    float* __restrict__ out)
{
    const int n = blockIdx.x * 256 + threadIdx.x;
    const int c = (int)lbl[n];
    float cnt  = fmaxf(g_cnt[c] * (float)N_COLS, 1.0f);
    float mean = g_sum[c] / cnt;
    float var  = fmaxf(g_sq[c] / cnt - mean * mean, 0.0f);
    float mm   = 0.5f * sqrtf(var);
    float x    = row_lc[n];
    float xm   = x - mm;
    float val  = (x > 0.f) ? (xm / S_CONST) : (xm * S_CONST);
    float a    = row_lse[n];
    float M    = fmaxf(a, val);
    float nll  = logf(expf(a - M) + expf(val - M)) + M - val;

    __shared__ float sh[4];
    float w = wred_sum(nll);
    int wave = threadIdx.x >> 6, lane = threadIdx.x & 63;
    if (lane == 0) sh[wave] = w;
    __syncthreads();
    if (threadIdx.x == 0)
        atomicAdd(out, (sh[0] + sh[1] + sh[2] + sh[3]) * (1.0f / (float)N_ROWS));
}

extern "C" void kernel_launch(void* const* d_in, const int* in_sizes, int n_in,
                              void* d_out, int out_size, void* d_ws, size_t ws_size,
                              hipStream_t stream) {
    const float*     X   = (const float*)d_in[0];
    const long long* lbl = (const long long*)d_in[1];
    float*           out = (float*)d_out;
    float*           ws  = (float*)d_ws;

    const int C = N_COLS, N = N_ROWS;
    float* g_sum   = ws;
    float* g_sq    = ws + C;
    float* g_cnt   = ws + 2 * C;
    float* row_lse = ws + 3 * C;
    float* row_lc  = row_lse + N;

    k_init<<<(3 * C + 255) / 256, 256, 0, stream>>>(ws, out);
    k_rowpass<<<N / 4, 256, 0, stream>>>(X, lbl, g_sum, g_sq, g_cnt,
                                         row_lse, row_lc);
    k_nll<<<N / 256, 256, 0, stream>>>(lbl, g_sum, g_sq, g_cnt,
                                       row_lse, row_lc, out);
}